// Round 1
// baseline (5960.294 us; speedup 1.0000x reference)
//
#include <hip/hip_runtime.h>
#include <hip/hip_bf16.h>
#include <math.h>

#define SEQ    2048
#define HIDDEN 4096
#define NH     32
#define HD     128
#define SCALE  0.08838834764831845f   // 1/sqrt(128)
#define CAND   1844                   // SEQ - recent_budget
#define KEEP   204                    // heavy_budget survivors among CAND

// ---------------------------------------------------------------------------
// SGEMM: C[M][N] = A[M][K] * B[K][N], fp32 row-major, M%128==0, N%128==0, K%16==0
// 128x128 tile, BK=16, 256 threads, 8x8 micro-tile.
// ---------------------------------------------------------------------------
__global__ __launch_bounds__(256) void sgemm_nn(const float* __restrict__ A,
                                                const float* __restrict__ B,
                                                float* __restrict__ C,
                                                int M, int N, int K) {
    __shared__ float as[16][128];   // as[k][m] (A staged transposed)
    __shared__ float bs[16][128];   // bs[k][n]
    const int tid = threadIdx.x;
    const int bm = blockIdx.y * 128;
    const int bn = blockIdx.x * 128;
    const int ty = tid >> 4, tx = tid & 15;

    float acc[8][8];
#pragma unroll
    for (int i = 0; i < 8; ++i)
#pragma unroll
        for (int j = 0; j < 8; ++j) acc[i][j] = 0.f;

    const int ar = tid >> 1;            // 0..127
    const int ac = (tid & 1) * 8;       // 0 or 8
    const int brow = tid >> 4;          // 0..15
    const int bcol = (tid & 15) * 8;    // 0..120

    for (int k0 = 0; k0 < K; k0 += 16) {
        float4 a0 = *(const float4*)&A[(size_t)(bm + ar) * K + k0 + ac];
        float4 a1 = *(const float4*)&A[(size_t)(bm + ar) * K + k0 + ac + 4];
        as[ac + 0][ar] = a0.x; as[ac + 1][ar] = a0.y;
        as[ac + 2][ar] = a0.z; as[ac + 3][ar] = a0.w;
        as[ac + 4][ar] = a1.x; as[ac + 5][ar] = a1.y;
        as[ac + 6][ar] = a1.z; as[ac + 7][ar] = a1.w;
        float4 b0 = *(const float4*)&B[(size_t)(k0 + brow) * N + bn + bcol];
        float4 b1 = *(const float4*)&B[(size_t)(k0 + brow) * N + bn + bcol + 4];
        *(float4*)&bs[brow][bcol] = b0;
        *(float4*)&bs[brow][bcol + 4] = b1;
        __syncthreads();
#pragma unroll
        for (int kk = 0; kk < 16; ++kk) {
            float4 af0 = *(const float4*)&as[kk][ty * 8];
            float4 af1 = *(const float4*)&as[kk][ty * 8 + 4];
            float4 bf0 = *(const float4*)&bs[kk][tx * 4];       // cols tx*4..+3
            float4 bf1 = *(const float4*)&bs[kk][64 + tx * 4];  // cols 64+tx*4..+3
            float a[8] = {af0.x, af0.y, af0.z, af0.w, af1.x, af1.y, af1.z, af1.w};
            float b[8] = {bf0.x, bf0.y, bf0.z, bf0.w, bf1.x, bf1.y, bf1.z, bf1.w};
#pragma unroll
            for (int i = 0; i < 8; ++i)
#pragma unroll
                for (int j = 0; j < 8; ++j) acc[i][j] += a[i] * b[j];
        }
        __syncthreads();
    }
#pragma unroll
    for (int i = 0; i < 8; ++i) {
        float4 c0 = make_float4(acc[i][0], acc[i][1], acc[i][2], acc[i][3]);
        float4 c1 = make_float4(acc[i][4], acc[i][5], acc[i][6], acc[i][7]);
        size_t row = (size_t)(bm + ty * 8 + i) * N + bn;
        *(float4*)&C[row + tx * 4] = c0;
        *(float4*)&C[row + 64 + tx * 4] = c1;
    }
}

// ---------------------------------------------------------------------------
// RoPE in-place on Q and K (layout [S][H], col = h*128 + d).
// inv_freq computed in double then rounded to fp32 to track XLA's fp32 pow
// as closely as possible (1-ulp error here amplifies by pos<=2047).
// ---------------------------------------------------------------------------
__global__ __launch_bounds__(256) void rope_kernel(float* __restrict__ Q,
                                                   float* __restrict__ Kp,
                                                   const int* __restrict__ pos) {
    int t = blockIdx.x * blockDim.x + threadIdx.x;
    if (t >= SEQ * NH * 64) return;
    int j = t & 63;
    int h = (t >> 6) & (NH - 1);
    int s = t >> 11;
    float p = (float)pos[s];
    float pf = (float)pow(10000.0, (double)j / 64.0);
    float invf = 1.0f / pf;                 // mirrors 1.0 / (base ** x) in fp32
    float f = p * invf;                     // fp32, same as reference
    float c = cosf(f), sn = sinf(f);
    size_t base = (size_t)s * HIDDEN + h * HD + j;
    float q1 = Q[base], q2 = Q[base + 64];
    Q[base]      = q1 * c - q2 * sn;
    Q[base + 64] = q2 * c + q1 * sn;
    float k1 = Kp[base], k2 = Kp[base + 64];
    Kp[base]      = k1 * c - k2 * sn;
    Kp[base + 64] = k2 * c + k1 * sn;
}

// ---------------------------------------------------------------------------
// Flash attention forward (fp32, causal). Grid (qb=32, h=32), 256 threads.
// BQ=64, BK=32. Q read straight from global (16-lane broadcast, L1-resident).
// Writes ctx[S][H], and per-row softmax stats m,l for the colsum pass.
// ---------------------------------------------------------------------------
__global__ __launch_bounds__(256) void flash_kernel(const float* __restrict__ Qf,
                                                    const float* __restrict__ Kf,
                                                    const float* __restrict__ Vf,
                                                    float* __restrict__ ctx,
                                                    float* __restrict__ mbuf,
                                                    float* __restrict__ lbuf) {
    __shared__ float k_s[32][129];
    __shared__ float v_s[32][132];
    __shared__ float p_s[64][33];
    const int h = blockIdx.y, qb = blockIdx.x;
    const int q0 = qb * 64;
    const int tid = threadIdx.x;
    const int ty = tid >> 4, tx = tid & 15;

    float m_run[4], l_run[4], o[4][8];
#pragma unroll
    for (int i = 0; i < 4; ++i) {
        m_run[i] = -1e30f; l_run[i] = 0.f;
#pragma unroll
        for (int j = 0; j < 8; ++j) o[i][j] = 0.f;
    }

    const int nkt = 2 * qb + 2;            // k tiles of 32 covering k <= q0+63
    for (int kt = 0; kt < nkt; ++kt) {
        const int k0 = kt * 32;
        for (int l = tid; l < 32 * 128; l += 256) {
            int r = l >> 7, c = l & 127;
            k_s[r][c] = Kf[(size_t)(k0 + r) * HIDDEN + h * HD + c];
        }
        for (int l = tid; l < 32 * 32; l += 256) {
            int r = l >> 5, c4 = (l & 31) << 2;
            *(float4*)&v_s[r][c4] = *(const float4*)&Vf[(size_t)(k0 + r) * HIDDEN + h * HD + c4];
        }
        __syncthreads();

        // S tile 64x32: rows ty*4+i, cols tx*2+j
        float s[4][2] = {{0.f, 0.f}, {0.f, 0.f}, {0.f, 0.f}, {0.f, 0.f}};
        for (int d0 = 0; d0 < 128; d0 += 8) {
            float qr[4][8];
#pragma unroll
            for (int i = 0; i < 4; ++i) {
                const float* qrow = &Qf[(size_t)(q0 + ty * 4 + i) * HIDDEN + h * HD + d0];
                float4 qa = *(const float4*)qrow;
                float4 qb4 = *(const float4*)(qrow + 4);
                qr[i][0] = qa.x; qr[i][1] = qa.y; qr[i][2] = qa.z; qr[i][3] = qa.w;
                qr[i][4] = qb4.x; qr[i][5] = qb4.y; qr[i][6] = qb4.z; qr[i][7] = qb4.w;
            }
#pragma unroll
            for (int dd = 0; dd < 8; ++dd) {
                float kr0 = k_s[tx * 2 + 0][d0 + dd];
                float kr1 = k_s[tx * 2 + 1][d0 + dd];
#pragma unroll
                for (int i = 0; i < 4; ++i) {
                    s[i][0] += qr[i][dd] * kr0;
                    s[i][1] += qr[i][dd] * kr1;
                }
            }
        }

#pragma unroll
        for (int i = 0; i < 4; ++i) {
            const int qq = q0 + ty * 4 + i;
            float s0 = (k0 + tx * 2 + 0 <= qq) ? s[i][0] * SCALE : -1e30f;
            float s1 = (k0 + tx * 2 + 1 <= qq) ? s[i][1] * SCALE : -1e30f;
            float rm = fmaxf(s0, s1);
            rm = fmaxf(rm, __shfl_xor(rm, 1));
            rm = fmaxf(rm, __shfl_xor(rm, 2));
            rm = fmaxf(rm, __shfl_xor(rm, 4));
            rm = fmaxf(rm, __shfl_xor(rm, 8));
            float mnew = fmaxf(m_run[i], rm);
            float corr = expf(m_run[i] - mnew);
            float p0 = expf(s0 - mnew);
            float p1 = expf(s1 - mnew);
            float rs = p0 + p1;
            rs += __shfl_xor(rs, 1);
            rs += __shfl_xor(rs, 2);
            rs += __shfl_xor(rs, 4);
            rs += __shfl_xor(rs, 8);
            l_run[i] = l_run[i] * corr + rs;
            m_run[i] = mnew;
#pragma unroll
            for (int j2 = 0; j2 < 8; ++j2) o[i][j2] *= corr;
            p_s[ty * 4 + i][tx * 2 + 0] = p0;
            p_s[ty * 4 + i][tx * 2 + 1] = p1;
        }
        __syncthreads();

        // PV: o[i][0..3] -> cols tx*4..+3 ; o[i][4..7] -> cols 64+tx*4..+3
#pragma unroll 4
        for (int kk = 0; kk < 32; ++kk) {
            float4 v0 = *(const float4*)&v_s[kk][tx * 4];
            float4 v1 = *(const float4*)&v_s[kk][64 + tx * 4];
#pragma unroll
            for (int i = 0; i < 4; ++i) {
                float pv = p_s[ty * 4 + i][kk];
                o[i][0] += pv * v0.x; o[i][1] += pv * v0.y;
                o[i][2] += pv * v0.z; o[i][3] += pv * v0.w;
                o[i][4] += pv * v1.x; o[i][5] += pv * v1.y;
                o[i][6] += pv * v1.z; o[i][7] += pv * v1.w;
            }
        }
        __syncthreads();
    }

#pragma unroll
    for (int i = 0; i < 4; ++i) {
        float inv = 1.f / l_run[i];
        float4 c0 = make_float4(o[i][0] * inv, o[i][1] * inv, o[i][2] * inv, o[i][3] * inv);
        float4 c1 = make_float4(o[i][4] * inv, o[i][5] * inv, o[i][6] * inv, o[i][7] * inv);
        size_t rowoff = (size_t)(q0 + ty * 4 + i) * HIDDEN + h * HD;
        *(float4*)&ctx[rowoff + tx * 4] = c0;
        *(float4*)&ctx[rowoff + 64 + tx * 4] = c1;
        if (tx == 0) {
            mbuf[h * SEQ + q0 + ty * 4 + i] = m_run[i];
            lbuf[h * SEQ + q0 + ty * 4 + i] = l_run[i];
        }
    }
}

// ---------------------------------------------------------------------------
// Column sums of the softmax matrix: prev[h][k] = sum_q attn[h][q][k].
// Grid (kb=32, h=32). K tile staged once; Q streamed from global; uses (m,l).
// Deterministic (no atomics).
// ---------------------------------------------------------------------------
__global__ __launch_bounds__(256) void colsum_kernel(const float* __restrict__ Qf,
                                                     const float* __restrict__ Kf,
                                                     const float* __restrict__ mbuf,
                                                     const float* __restrict__ lbuf,
                                                     float* __restrict__ prev) {
    __shared__ float k_s[64][129];
    __shared__ float red[16][68];
    const int h = blockIdx.y, kb = blockIdx.x;
    const int k0 = kb * 64;
    const int tid = threadIdx.x;
    const int ty = tid >> 4, tx = tid & 15;

    for (int l = tid; l < 64 * 128; l += 256) {
        int r = l >> 7, c = l & 127;
        k_s[r][c] = Kf[(size_t)(k0 + r) * HIDDEN + h * HD + c];
    }
    __syncthreads();

    float csum[4] = {0.f, 0.f, 0.f, 0.f};
    for (int qb = kb; qb < SEQ / 64; ++qb) {
        const int q0 = qb * 64;
        float mi[4], rli[4];
#pragma unroll
        for (int i = 0; i < 4; ++i) {
            mi[i]  = mbuf[h * SEQ + q0 + ty * 4 + i];
            rli[i] = 1.f / lbuf[h * SEQ + q0 + ty * 4 + i];
        }
        float s[4][4] = {};
        for (int d0 = 0; d0 < 128; d0 += 8) {
            float qr[4][8];
#pragma unroll
            for (int i = 0; i < 4; ++i) {
                const float* qrow = &Qf[(size_t)(q0 + ty * 4 + i) * HIDDEN + h * HD + d0];
                float4 qa = *(const float4*)qrow;
                float4 qb4 = *(const float4*)(qrow + 4);
                qr[i][0] = qa.x; qr[i][1] = qa.y; qr[i][2] = qa.z; qr[i][3] = qa.w;
                qr[i][4] = qb4.x; qr[i][5] = qb4.y; qr[i][6] = qb4.z; qr[i][7] = qb4.w;
            }
#pragma unroll
            for (int dd = 0; dd < 8; ++dd) {
                float kr[4];
#pragma unroll
                for (int j = 0; j < 4; ++j) kr[j] = k_s[tx * 4 + j][d0 + dd];
#pragma unroll
                for (int i = 0; i < 4; ++i)
#pragma unroll
                    for (int j = 0; j < 4; ++j) s[i][j] += qr[i][dd] * kr[j];
            }
        }
#pragma unroll
        for (int i = 0; i < 4; ++i) {
            const int qq = q0 + ty * 4 + i;
#pragma unroll
            for (int j = 0; j < 4; ++j) {
                if (k0 + tx * 4 + j <= qq)
                    csum[j] += expf(s[i][j] * SCALE - mi[i]) * rli[i];
            }
        }
    }
#pragma unroll
    for (int j = 0; j < 4; ++j) red[ty][tx * 4 + j] = csum[j];
    __syncthreads();
    if (tid < 64) {
        float acc = 0.f;
#pragma unroll
        for (int t = 0; t < 16; ++t) acc += red[t][tid];
        prev[h * SEQ + k0 + tid] = acc;
    }
}

// ---------------------------------------------------------------------------
// Per-head exact selection: keep top-204 of first 1844 scores (ties -> higher
// index preserved, matching jax.lax.top_k evicting lower index first), plus
// the last 204 positions. Full bitonic sort of (score, idx), 1 block/head.
// ---------------------------------------------------------------------------
__global__ __launch_bounds__(256) void topk_kernel(const float* __restrict__ prev,
                                                   float* __restrict__ pres) {
    __shared__ float sk[2048];
    __shared__ int   si[2048];
    __shared__ unsigned char flag[2048];
    const int h = blockIdx.x, tid = threadIdx.x;
    for (int i = tid; i < 2048; i += 256) {
        sk[i] = (i < CAND) ? prev[h * SEQ + i] : -INFINITY;
        si[i] = i;
        flag[i] = 0;
    }
    __syncthreads();
    for (int k = 2; k <= 2048; k <<= 1) {
        for (int j = k >> 1; j > 0; j >>= 1) {
            for (int i = tid; i < 2048; i += 256) {
                int ixj = i ^ j;
                if (ixj > i) {
                    bool up = ((i & k) == 0);
                    float ka = sk[i], kb_ = sk[ixj];
                    int ia = si[i], ib = si[ixj];
                    // "after": element should come later in descending-(score,idx) order
                    bool after = (ka < kb_) || (ka == kb_ && ia < ib);
                    if (after == up) {
                        sk[i] = kb_; sk[ixj] = ka;
                        si[i] = ib;  si[ixj] = ia;
                    }
                }
            }
            __syncthreads();
        }
    }
    if (tid < KEEP) flag[si[tid]] = 1;
    __syncthreads();
    for (int i = tid; i < 2048; i += 256)
        pres[h * SEQ + i] = (i >= CAND || flag[i]) ? 1.0f : 0.0f;
}

// ---------------------------------------------------------------------------
extern "C" void kernel_launch(void* const* d_in, const int* in_sizes, int n_in,
                              void* d_out, int out_size, void* d_ws, size_t ws_size,
                              hipStream_t stream) {
    const float* X  = (const float*)d_in[0];
    const int*   pos = (const int*)d_in[1];
    const float* Wq = (const float*)d_in[2];
    const float* Wk = (const float*)d_in[3];
    const float* Wv = (const float*)d_in[4];
    const float* Wo = (const float*)d_in[5];

    float* out  = (float*)d_out;                        // [S][H]
    float* prev = out + (size_t)SEQ * HIDDEN;           // [NH][S]
    float* pres = prev + (size_t)NH * SEQ;              // [NH][S]

    float* Qb = (float*)d_ws;                           // [S][H]
    float* Kb = Qb + (size_t)SEQ * HIDDEN;
    float* Vb = Kb + (size_t)SEQ * HIDDEN;
    float* Cb = Vb + (size_t)SEQ * HIDDEN;              // attention ctx [S][H]
    float* mb = Cb + (size_t)SEQ * HIDDEN;              // [NH][S]
    float* lb = mb + (size_t)NH * SEQ;                  // [NH][S]

    dim3 gg(HIDDEN / 128, SEQ / 128);
    sgemm_nn<<<gg, 256, 0, stream>>>(X, Wq, Qb, SEQ, HIDDEN, HIDDEN);
    sgemm_nn<<<gg, 256, 0, stream>>>(X, Wk, Kb, SEQ, HIDDEN, HIDDEN);
    sgemm_nn<<<gg, 256, 0, stream>>>(X, Wv, Vb, SEQ, HIDDEN, HIDDEN);

    int nt = SEQ * NH * 64;
    rope_kernel<<<(nt + 255) / 256, 256, 0, stream>>>(Qb, Kb, pos);

    flash_kernel<<<dim3(SEQ / 64, NH), 256, 0, stream>>>(Qb, Kb, Vb, Cb, mb, lb);
    colsum_kernel<<<dim3(SEQ / 64, NH), 256, 0, stream>>>(Qb, Kb, mb, lb, prev);

    sgemm_nn<<<gg, 256, 0, stream>>>(Cb, Wo, out, SEQ, HIDDEN, HIDDEN);

    topk_kernel<<<NH, 256, 0, stream>>>(prev, pres);
}

// Round 3
// 4080.194 us; speedup vs baseline: 1.4608x; 1.4608x over previous
//
#include <hip/hip_runtime.h>
#include <hip/hip_bf16.h>
#include <math.h>

#define SEQ    2048
#define HIDDEN 4096
#define NH     32
#define HD     128
#define SCALE  0.08838834764831845f   // 1/sqrt(128)
#define CAND   1844                   // SEQ - recent_budget
#define KEEP   204                    // heavy_budget survivors among CAND

typedef short bf16x8 __attribute__((ext_vector_type(8)));
typedef float f32x4  __attribute__((ext_vector_type(4)));

__device__ __forceinline__ ushort f2bf(float x) {   // round-to-nearest-even
    uint u = __float_as_uint(x);
    u += 0x7fffu + ((u >> 16) & 1u);
    return (ushort)(u >> 16);
}
__device__ __forceinline__ float bf2f(ushort h) {
    return __uint_as_float(((uint)h) << 16);
}

#define GLOAD_LDS16(gp, lp)                                                  \
    __builtin_amdgcn_global_load_lds(                                        \
        (const __attribute__((address_space(1))) void*)(gp),                 \
        (__attribute__((address_space(3))) void*)(lp), 16, 0, 0)

// ---------------------------------------------------------------------------
// split2_rows: fp32 [R][C] -> bf16 hi[R][C], lo[R][C]
// ---------------------------------------------------------------------------
__global__ __launch_bounds__(256) void split2_rows(const float* __restrict__ in,
                                                   ushort* __restrict__ hi_o,
                                                   ushort* __restrict__ lo_o,
                                                   int n4) {
    int t = blockIdx.x * 256 + threadIdx.x;
    if (t >= n4) return;
    float4 v = *(const float4*)&in[(size_t)t * 4];
    ushort4 hi, lo;
    hi.x = f2bf(v.x); lo.x = f2bf(v.x - bf2f(hi.x));
    hi.y = f2bf(v.y); lo.y = f2bf(v.y - bf2f(hi.y));
    hi.z = f2bf(v.z); lo.z = f2bf(v.z - bf2f(hi.z));
    hi.w = f2bf(v.w); lo.w = f2bf(v.w - bf2f(hi.w));
    *(ushort4*)&hi_o[(size_t)t * 4] = hi;
    *(ushort4*)&lo_o[(size_t)t * 4] = lo;
}

// ---------------------------------------------------------------------------
// split2_tr: W fp32 [K=4096][N=4096] -> Bt_hi[N][K], Bt_lo[N][K] (bf16)
// 64x64 LDS-tiled transpose + split.
// ---------------------------------------------------------------------------
__global__ __launch_bounds__(256) void split2_tr(const float* __restrict__ W,
                                                 ushort* __restrict__ hi_o,
                                                 ushort* __restrict__ lo_o) {
    __shared__ float t_s[64][65];
    const int tid = threadIdx.x;
    const int kb = blockIdx.y * 64, nb = blockIdx.x * 64;
    for (int i = tid; i < 64 * 16; i += 256) {
        int r = i >> 4, c4 = (i & 15) * 4;
        float4 v = *(const float4*)&W[(size_t)(kb + r) * HIDDEN + nb + c4];
        t_s[r][c4 + 0] = v.x; t_s[r][c4 + 1] = v.y;
        t_s[r][c4 + 2] = v.z; t_s[r][c4 + 3] = v.w;
    }
    __syncthreads();
    for (int i = tid; i < 64 * 16; i += 256) {
        int rn = i >> 4, k4 = (i & 15) * 4;
        float x0 = t_s[k4 + 0][rn], x1 = t_s[k4 + 1][rn];
        float x2 = t_s[k4 + 2][rn], x3 = t_s[k4 + 3][rn];
        ushort4 hi, lo;
        hi.x = f2bf(x0); lo.x = f2bf(x0 - bf2f(hi.x));
        hi.y = f2bf(x1); lo.y = f2bf(x1 - bf2f(hi.y));
        hi.z = f2bf(x2); lo.z = f2bf(x2 - bf2f(hi.z));
        hi.w = f2bf(x3); lo.w = f2bf(x3 - bf2f(hi.w));
        size_t ro = (size_t)(nb + rn) * HIDDEN + kb + k4;
        *(ushort4*)&hi_o[ro] = hi;
        *(ushort4*)&lo_o[ro] = lo;
    }
}

// ---------------------------------------------------------------------------
// gemm3seg_nt: C[2048][4096] fp32 = sum of 3 bf16 NT GEMM segments:
//   seg0: Ahi * Bhi^T   seg1: Alo * Bhi^T   seg2: Ahi * Blo^T
// (Markidis 3-term split; drops only lo*lo ~ 2^-18 rel.)
// m97 structure: 128x128 tile, BK=32, 4 waves (2x2 of 64x64), LDS dbuf via
// global_load_lds width 16, one barrier per K-step. 384 K-steps total.
// ---------------------------------------------------------------------------
__global__ __launch_bounds__(256) void gemm3seg_nt(const ushort* __restrict__ Ahi,
                                                   const ushort* __restrict__ Alo,
                                                   const ushort* __restrict__ Bhi,
                                                   const ushort* __restrict__ Blo,
                                                   float* __restrict__ C) {
    __shared__ __align__(16) ushort As[2][128 * 32];
    __shared__ __align__(16) ushort Bs[2][128 * 32];
    const int tid = threadIdx.x, lane = tid & 63, wv = tid >> 6;
    const int wr = wv >> 1, wc = wv & 1;
    const int bm = blockIdx.y * 128, bn = blockIdx.x * 128;
    const int r15 = lane & 15, kg = lane >> 4;

    // per-thread staging bases (row*K + ks), two chunks per operand
    const int cb0 = wv, cb1 = 4 + wv;
    const int c0 = cb0 * 64 + lane, c1 = cb1 * 64 + lane;
    const size_t aOff0 = (size_t)(bm + (c0 >> 2)) * HIDDEN + (c0 & 3) * 8;
    const size_t aOff1 = (size_t)(bm + (c1 >> 2)) * HIDDEN + (c1 & 3) * 8;
    const size_t bOff0 = (size_t)(bn + (c0 >> 2)) * HIDDEN + (c0 & 3) * 8;
    const size_t bOff1 = (size_t)(bn + (c1 >> 2)) * HIDDEN + (c1 & 3) * 8;
    const int ldsA0 = cb0 * 512, ldsA1 = cb1 * 512;   // ushort index

    f32x4 acc[4][4];
#pragma unroll
    for (int i = 0; i < 4; ++i)
#pragma unroll
        for (int j = 0; j < 4; ++j) {
            f32x4 z = {0.f, 0.f, 0.f, 0.f};
            acc[i][j] = z;
        }

#define STAGE(b, tt)                                                          \
    {                                                                         \
        const int seg = (tt) >> 7;                                            \
        const int k0  = ((tt) & 127) * 32;                                    \
        const ushort* aP = (seg == 1) ? Alo : Ahi;                            \
        const ushort* bP = (seg == 2) ? Blo : Bhi;                            \
        GLOAD_LDS16(aP + aOff0 + k0, &As[b][ldsA0]);                          \
        GLOAD_LDS16(bP + bOff0 + k0, &Bs[b][ldsA0]);                          \
        GLOAD_LDS16(aP + aOff1 + k0, &As[b][ldsA1]);                          \
        GLOAD_LDS16(bP + bOff1 + k0, &Bs[b][ldsA1]);                          \
    }

    STAGE(0, 0)
    int buf = 0;
    for (int tt = 0; tt < 384; ++tt) {
        __syncthreads();                 // compiler drains vmcnt -> buf ready
        if (tt + 1 < 384) STAGE(buf ^ 1, tt + 1)
        bf16x8 af[4], bfr[4];
#pragma unroll
        for (int i = 0; i < 4; ++i) {
            af[i]  = *(const bf16x8*)&As[buf][(wr * 64 + i * 16 + r15) * 32 + kg * 8];
            bfr[i] = *(const bf16x8*)&Bs[buf][(wc * 64 + i * 16 + r15) * 32 + kg * 8];
        }
#pragma unroll
        for (int i = 0; i < 4; ++i)
#pragma unroll
            for (int j = 0; j < 4; ++j)
                acc[i][j] = __builtin_amdgcn_mfma_f32_16x16x32_bf16(
                    af[i], bfr[j], acc[i][j], 0, 0, 0);
        buf ^= 1;
    }
#undef STAGE

#pragma unroll
    for (int i = 0; i < 4; ++i) {
        int row0 = bm + wr * 64 + i * 16 + kg * 4;
#pragma unroll
        for (int j = 0; j < 4; ++j) {
            int col = bn + wc * 64 + j * 16 + r15;
#pragma unroll
            for (int r = 0; r < 4; ++r)
                C[(size_t)(row0 + r) * HIDDEN + col] = acc[i][j][r];
        }
    }
}

// ---------------------------------------------------------------------------
// SGEMM fallback (R1 fp32 path, known-correct): C = A[M][K] * B[K][N]
// ---------------------------------------------------------------------------
__global__ __launch_bounds__(256) void sgemm_nn(const float* __restrict__ A,
                                                const float* __restrict__ B,
                                                float* __restrict__ C,
                                                int M, int N, int K) {
    __shared__ float as[16][128];
    __shared__ float bs[16][128];
    const int tid = threadIdx.x;
    const int bm = blockIdx.y * 128;
    const int bn = blockIdx.x * 128;
    const int ty = tid >> 4, tx = tid & 15;

    float acc[8][8];
#pragma unroll
    for (int i = 0; i < 8; ++i)
#pragma unroll
        for (int j = 0; j < 8; ++j) acc[i][j] = 0.f;

    const int ar = tid >> 1;
    const int ac = (tid & 1) * 8;
    const int brow = tid >> 4;
    const int bcol = (tid & 15) * 8;

    for (int k0 = 0; k0 < K; k0 += 16) {
        float4 a0 = *(const float4*)&A[(size_t)(bm + ar) * K + k0 + ac];
        float4 a1 = *(const float4*)&A[(size_t)(bm + ar) * K + k0 + ac + 4];
        as[ac + 0][ar] = a0.x; as[ac + 1][ar] = a0.y;
        as[ac + 2][ar] = a0.z; as[ac + 3][ar] = a0.w;
        as[ac + 4][ar] = a1.x; as[ac + 5][ar] = a1.y;
        as[ac + 6][ar] = a1.z; as[ac + 7][ar] = a1.w;
        float4 b0 = *(const float4*)&B[(size_t)(k0 + brow) * N + bn + bcol];
        float4 b1 = *(const float4*)&B[(size_t)(k0 + brow) * N + bn + bcol + 4];
        *(float4*)&bs[brow][bcol] = b0;
        *(float4*)&bs[brow][bcol + 4] = b1;
        __syncthreads();
#pragma unroll
        for (int kk = 0; kk < 16; ++kk) {
            float4 af0 = *(const float4*)&as[kk][ty * 8];
            float4 af1 = *(const float4*)&as[kk][ty * 8 + 4];
            float4 bf0 = *(const float4*)&bs[kk][tx * 4];
            float4 bf1 = *(const float4*)&bs[kk][64 + tx * 4];
            float a[8] = {af0.x, af0.y, af0.z, af0.w, af1.x, af1.y, af1.z, af1.w};
            float b[8] = {bf0.x, bf0.y, bf0.z, bf0.w, bf1.x, bf1.y, bf1.z, bf1.w};
#pragma unroll
            for (int i = 0; i < 8; ++i)
#pragma unroll
                for (int j = 0; j < 8; ++j) acc[i][j] += a[i] * b[j];
        }
        __syncthreads();
    }
#pragma unroll
    for (int i = 0; i < 8; ++i) {
        float4 c0 = make_float4(acc[i][0], acc[i][1], acc[i][2], acc[i][3]);
        float4 c1 = make_float4(acc[i][4], acc[i][5], acc[i][6], acc[i][7]);
        size_t row = (size_t)(bm + ty * 8 + i) * N + bn;
        *(float4*)&C[row + tx * 4] = c0;
        *(float4*)&C[row + 64 + tx * 4] = c1;
    }
}

// ---------------------------------------------------------------------------
// RoPE in-place on Q and K (layout [S][H], col = h*128 + d). (unchanged)
// ---------------------------------------------------------------------------
__global__ __launch_bounds__(256) void rope_kernel(float* __restrict__ Q,
                                                   float* __restrict__ Kp,
                                                   const int* __restrict__ pos) {
    int t = blockIdx.x * blockDim.x + threadIdx.x;
    if (t >= SEQ * NH * 64) return;
    int j = t & 63;
    int h = (t >> 6) & (NH - 1);
    int s = t >> 11;
    float p = (float)pos[s];
    float pf = (float)pow(10000.0, (double)j / 64.0);
    float invf = 1.0f / pf;
    float f = p * invf;
    float c = cosf(f), sn = sinf(f);
    size_t base = (size_t)s * HIDDEN + h * HD + j;
    float q1 = Q[base], q2 = Q[base + 64];
    Q[base]      = q1 * c - q2 * sn;
    Q[base + 64] = q2 * c + q1 * sn;
    float k1 = Kp[base], k2 = Kp[base + 64];
    Kp[base]      = k1 * c - k2 * sn;
    Kp[base + 64] = k2 * c + k1 * sn;
}

// ---------------------------------------------------------------------------
// Flash attention forward (fp32, causal). (unchanged from passing R1 version)
// ---------------------------------------------------------------------------
__global__ __launch_bounds__(256) void flash_kernel(const float* __restrict__ Qf,
                                                    const float* __restrict__ Kf,
                                                    const float* __restrict__ Vf,
                                                    float* __restrict__ ctx,
                                                    float* __restrict__ mbuf,
                                                    float* __restrict__ lbuf) {
    __shared__ float k_s[32][129];
    __shared__ float v_s[32][132];
    __shared__ float p_s[64][33];
    const int h = blockIdx.y, qb = blockIdx.x;
    const int q0 = qb * 64;
    const int tid = threadIdx.x;
    const int ty = tid >> 4, tx = tid & 15;

    float m_run[4], l_run[4], o[4][8];
#pragma unroll
    for (int i = 0; i < 4; ++i) {
        m_run[i] = -1e30f; l_run[i] = 0.f;
#pragma unroll
        for (int j = 0; j < 8; ++j) o[i][j] = 0.f;
    }

    const int nkt = 2 * qb + 2;
    for (int kt = 0; kt < nkt; ++kt) {
        const int k0 = kt * 32;
        for (int l = tid; l < 32 * 128; l += 256) {
            int r = l >> 7, c = l & 127;
            k_s[r][c] = Kf[(size_t)(k0 + r) * HIDDEN + h * HD + c];
        }
        for (int l = tid; l < 32 * 32; l += 256) {
            int r = l >> 5, c4 = (l & 31) << 2;
            *(float4*)&v_s[r][c4] = *(const float4*)&Vf[(size_t)(k0 + r) * HIDDEN + h * HD + c4];
        }
        __syncthreads();

        float s[4][2] = {{0.f, 0.f}, {0.f, 0.f}, {0.f, 0.f}, {0.f, 0.f}};
        for (int d0 = 0; d0 < 128; d0 += 8) {
            float qr[4][8];
#pragma unroll
            for (int i = 0; i < 4; ++i) {
                const float* qrow = &Qf[(size_t)(q0 + ty * 4 + i) * HIDDEN + h * HD + d0];
                float4 qa = *(const float4*)qrow;
                float4 qb4 = *(const float4*)(qrow + 4);
                qr[i][0] = qa.x; qr[i][1] = qa.y; qr[i][2] = qa.z; qr[i][3] = qa.w;
                qr[i][4] = qb4.x; qr[i][5] = qb4.y; qr[i][6] = qb4.z; qr[i][7] = qb4.w;
            }
#pragma unroll
            for (int dd = 0; dd < 8; ++dd) {
                float kr0 = k_s[tx * 2 + 0][d0 + dd];
                float kr1 = k_s[tx * 2 + 1][d0 + dd];
#pragma unroll
                for (int i = 0; i < 4; ++i) {
                    s[i][0] += qr[i][dd] * kr0;
                    s[i][1] += qr[i][dd] * kr1;
                }
            }
        }

#pragma unroll
        for (int i = 0; i < 4; ++i) {
            const int qq = q0 + ty * 4 + i;
            float s0 = (k0 + tx * 2 + 0 <= qq) ? s[i][0] * SCALE : -1e30f;
            float s1 = (k0 + tx * 2 + 1 <= qq) ? s[i][1] * SCALE : -1e30f;
            float rm = fmaxf(s0, s1);
            rm = fmaxf(rm, __shfl_xor(rm, 1));
            rm = fmaxf(rm, __shfl_xor(rm, 2));
            rm = fmaxf(rm, __shfl_xor(rm, 4));
            rm = fmaxf(rm, __shfl_xor(rm, 8));
            float mnew = fmaxf(m_run[i], rm);
            float corr = expf(m_run[i] - mnew);
            float p0 = expf(s0 - mnew);
            float p1 = expf(s1 - mnew);
            float rs = p0 + p1;
            rs += __shfl_xor(rs, 1);
            rs += __shfl_xor(rs, 2);
            rs += __shfl_xor(rs, 4);
            rs += __shfl_xor(rs, 8);
            l_run[i] = l_run[i] * corr + rs;
            m_run[i] = mnew;
#pragma unroll
            for (int j2 = 0; j2 < 8; ++j2) o[i][j2] *= corr;
            p_s[ty * 4 + i][tx * 2 + 0] = p0;
            p_s[ty * 4 + i][tx * 2 + 1] = p1;
        }
        __syncthreads();

#pragma unroll 4
        for (int kk = 0; kk < 32; ++kk) {
            float4 v0 = *(const float4*)&v_s[kk][tx * 4];
            float4 v1 = *(const float4*)&v_s[kk][64 + tx * 4];
#pragma unroll
            for (int i = 0; i < 4; ++i) {
                float pv = p_s[ty * 4 + i][kk];
                o[i][0] += pv * v0.x; o[i][1] += pv * v0.y;
                o[i][2] += pv * v0.z; o[i][3] += pv * v0.w;
                o[i][4] += pv * v1.x; o[i][5] += pv * v1.y;
                o[i][6] += pv * v1.z; o[i][7] += pv * v1.w;
            }
        }
        __syncthreads();
    }

#pragma unroll
    for (int i = 0; i < 4; ++i) {
        float inv = 1.f / l_run[i];
        float4 c0 = make_float4(o[i][0] * inv, o[i][1] * inv, o[i][2] * inv, o[i][3] * inv);
        float4 c1 = make_float4(o[i][4] * inv, o[i][5] * inv, o[i][6] * inv, o[i][7] * inv);
        size_t rowoff = (size_t)(q0 + ty * 4 + i) * HIDDEN + h * HD;
        *(float4*)&ctx[rowoff + tx * 4] = c0;
        *(float4*)&ctx[rowoff + 64 + tx * 4] = c1;
        if (tx == 0) {
            mbuf[h * SEQ + q0 + ty * 4 + i] = m_run[i];
            lbuf[h * SEQ + q0 + ty * 4 + i] = l_run[i];
        }
    }
}

// ---------------------------------------------------------------------------
// Column sums of softmax: prev[h][k] = sum_q attn[h][q][k]. (unchanged)
// ---------------------------------------------------------------------------
__global__ __launch_bounds__(256) void colsum_kernel(const float* __restrict__ Qf,
                                                     const float* __restrict__ Kf,
                                                     const float* __restrict__ mbuf,
                                                     const float* __restrict__ lbuf,
                                                     float* __restrict__ prev) {
    __shared__ float k_s[64][129];
    __shared__ float red[16][68];
    const int h = blockIdx.y, kb = blockIdx.x;
    const int k0 = kb * 64;
    const int tid = threadIdx.x;
    const int ty = tid >> 4, tx = tid & 15;

    for (int l = tid; l < 64 * 128; l += 256) {
        int r = l >> 7, c = l & 127;
        k_s[r][c] = Kf[(size_t)(k0 + r) * HIDDEN + h * HD + c];
    }
    __syncthreads();

    float csum[4] = {0.f, 0.f, 0.f, 0.f};
    for (int qb = kb; qb < SEQ / 64; ++qb) {
        const int q0 = qb * 64;
        float mi[4], rli[4];
#pragma unroll
        for (int i = 0; i < 4; ++i) {
            mi[i]  = mbuf[h * SEQ + q0 + ty * 4 + i];
            rli[i] = 1.f / lbuf[h * SEQ + q0 + ty * 4 + i];
        }
        float s[4][4] = {};
        for (int d0 = 0; d0 < 128; d0 += 8) {
            float qr[4][8];
#pragma unroll
            for (int i = 0; i < 4; ++i) {
                const float* qrow = &Qf[(size_t)(q0 + ty * 4 + i) * HIDDEN + h * HD + d0];
                float4 qa = *(const float4*)qrow;
                float4 qb4 = *(const float4*)(qrow + 4);
                qr[i][0] = qa.x; qr[i][1] = qa.y; qr[i][2] = qa.z; qr[i][3] = qa.w;
                qr[i][4] = qb4.x; qr[i][5] = qb4.y; qr[i][6] = qb4.z; qr[i][7] = qb4.w;
            }
#pragma unroll
            for (int dd = 0; dd < 8; ++dd) {
                float kr[4];
#pragma unroll
                for (int j = 0; j < 4; ++j) kr[j] = k_s[tx * 4 + j][d0 + dd];
#pragma unroll
                for (int i = 0; i < 4; ++i)
#pragma unroll
                    for (int j = 0; j < 4; ++j) s[i][j] += qr[i][dd] * kr[j];
            }
        }
#pragma unroll
        for (int i = 0; i < 4; ++i) {
            const int qq = q0 + ty * 4 + i;
#pragma unroll
            for (int j = 0; j < 4; ++j) {
                if (k0 + tx * 4 + j <= qq)
                    csum[j] += expf(s[i][j] * SCALE - mi[i]) * rli[i];
            }
        }
    }
#pragma unroll
    for (int j = 0; j < 4; ++j) red[ty][tx * 4 + j] = csum[j];
    __syncthreads();
    if (tid < 64) {
        float acc = 0.f;
#pragma unroll
        for (int t = 0; t < 16; ++t) acc += red[t][tid];
        prev[h * SEQ + k0 + tid] = acc;
    }
}

// ---------------------------------------------------------------------------
// Per-head exact top-204 selection (bitonic, ties -> higher index kept).
// (unchanged)
// ---------------------------------------------------------------------------
__global__ __launch_bounds__(256) void topk_kernel(const float* __restrict__ prev,
                                                   float* __restrict__ pres) {
    __shared__ float sk[2048];
    __shared__ int   si[2048];
    __shared__ unsigned char flag[2048];
    const int h = blockIdx.x, tid = threadIdx.x;
    for (int i = tid; i < 2048; i += 256) {
        sk[i] = (i < CAND) ? prev[h * SEQ + i] : -INFINITY;
        si[i] = i;
        flag[i] = 0;
    }
    __syncthreads();
    for (int k = 2; k <= 2048; k <<= 1) {
        for (int j = k >> 1; j > 0; j >>= 1) {
            for (int i = tid; i < 2048; i += 256) {
                int ixj = i ^ j;
                if (ixj > i) {
                    bool up = ((i & k) == 0);
                    float ka = sk[i], kb_ = sk[ixj];
                    int ia = si[i], ib = si[ixj];
                    bool after = (ka < kb_) || (ka == kb_ && ia < ib);
                    if (after == up) {
                        sk[i] = kb_; sk[ixj] = ka;
                        si[i] = ib;  si[ixj] = ia;
                    }
                }
            }
            __syncthreads();
        }
    }
    if (tid < KEEP) flag[si[tid]] = 1;
    __syncthreads();
    for (int i = tid; i < 2048; i += 256)
        pres[h * SEQ + i] = (i >= CAND || flag[i]) ? 1.0f : 0.0f;
}

// ---------------------------------------------------------------------------
extern "C" void kernel_launch(void* const* d_in, const int* in_sizes, int n_in,
                              void* d_out, int out_size, void* d_ws, size_t ws_size,
                              hipStream_t stream) {
    const float* X   = (const float*)d_in[0];
    const int*   pos = (const int*)d_in[1];
    const float* Wq  = (const float*)d_in[2];
    const float* Wk  = (const float*)d_in[3];
    const float* Wv  = (const float*)d_in[4];
    const float* Wo  = (const float*)d_in[5];

    float* out  = (float*)d_out;                        // [S][H]
    float* prev = out + (size_t)SEQ * HIDDEN;           // [NH][S]
    float* pres = prev + (size_t)NH * SEQ;              // [NH][S]

    // ---- common workspace region (all paths) -----------------------------
    char* w = (char*)d_ws;
    float* Qb = (float*)(w);                                    //  33.55 MB
    float* Kb = (float*)(w + 33554432);                         //  33.55 MB
    float* Vb = (float*)(w + 67108864);                         //  33.55 MB
    float* mb = (float*)(w + 100663296);                        //   0.26 MB
    float* lb = (float*)(w + 100925440);                        //   0.26 MB
    char*  pk = w + 101187584;                                  // packs / Cb

    const size_t NEED_MFMA = 201850880;   // + Ahi/Alo 33.55 + Bhi/Blo 67.11 MB
    const bool   use_mfma  = (ws_size >= NEED_MFMA);

    dim3 ggemm(HIDDEN / 128, SEQ / 128);

    if (use_mfma) {
        ushort* Ahi = (ushort*)(pk);                            // [S][H] 16.78 MB
        ushort* Alo = (ushort*)(pk + 16777216);                 // 16.78 MB
        ushort* Bhi = (ushort*)(pk + 33554432);                 // [N][K] 33.55 MB
        ushort* Blo = (ushort*)(pk + 67108864);                 // 33.55 MB
        float*  Cb  = (float*)Bhi;   // alias: Bhi dead during attention phase

        dim3 gsr((SEQ * HIDDEN / 4 + 255) / 256);
        dim3 gtr(HIDDEN / 64, HIDDEN / 64);

        split2_rows<<<gsr, 256, 0, stream>>>(X, Ahi, Alo, SEQ * HIDDEN / 4);

        split2_tr<<<gtr, 256, 0, stream>>>(Wq, Bhi, Blo);
        gemm3seg_nt<<<ggemm, 256, 0, stream>>>(Ahi, Alo, Bhi, Blo, Qb);
        split2_tr<<<gtr, 256, 0, stream>>>(Wk, Bhi, Blo);
        gemm3seg_nt<<<ggemm, 256, 0, stream>>>(Ahi, Alo, Bhi, Blo, Kb);
        split2_tr<<<gtr, 256, 0, stream>>>(Wv, Bhi, Blo);
        gemm3seg_nt<<<ggemm, 256, 0, stream>>>(Ahi, Alo, Bhi, Blo, Vb);

        int nt = SEQ * NH * 64;
        rope_kernel<<<(nt + 255) / 256, 256, 0, stream>>>(Qb, Kb, pos);

        flash_kernel<<<dim3(SEQ / 64, NH), 256, 0, stream>>>(Qb, Kb, Vb, Cb, mb, lb);
        colsum_kernel<<<dim3(SEQ / 64, NH), 256, 0, stream>>>(Qb, Kb, mb, lb, prev);

        split2_rows<<<gsr, 256, 0, stream>>>(Cb, Ahi, Alo, SEQ * HIDDEN / 4);
        split2_tr<<<gtr, 256, 0, stream>>>(Wo, Bhi, Blo);   // clobbers Cb (done)
        gemm3seg_nt<<<ggemm, 256, 0, stream>>>(Ahi, Alo, Bhi, Blo, out);

        topk_kernel<<<NH, 256, 0, stream>>>(prev, pres);
    } else {
        // fp32 fallback (R1 path, 134.7 MB)
        float* Cb = (float*)pk;                                 // 33.55 MB

        sgemm_nn<<<ggemm, 256, 0, stream>>>(X, Wq, Qb, SEQ, HIDDEN, HIDDEN);
        sgemm_nn<<<ggemm, 256, 0, stream>>>(X, Wk, Kb, SEQ, HIDDEN, HIDDEN);
        sgemm_nn<<<ggemm, 256, 0, stream>>>(X, Wv, Vb, SEQ, HIDDEN, HIDDEN);

        int nt = SEQ * NH * 64;
        rope_kernel<<<(nt + 255) / 256, 256, 0, stream>>>(Qb, Kb, pos);

        flash_kernel<<<dim3(SEQ / 64, NH), 256, 0, stream>>>(Qb, Kb, Vb, Cb, mb, lb);
        colsum_kernel<<<dim3(SEQ / 64, NH), 256, 0, stream>>>(Qb, Kb, mb, lb, prev);

        sgemm_nn<<<ggemm, 256, 0, stream>>>(Cb, Wo, out, SEQ, HIDDEN, HIDDEN);

        topk_kernel<<<NH, 256, 0, stream>>>(prev, pres);
    }
}